// Round 4
// baseline (27247.711 us; speedup 1.0000x reference)
//
#include <hip/hip_runtime.h>
#include <math.h>

#define NB   16    // batch
#define TE   256   // T_ENC
#define TD   200   // T_DEC
#define EE   512   // encoder dim
#define ATT  128
#define PREN 256
#define HH   1024
#define NMEL 80
#define NLOC 32
#define KWW  31
#define PADW 15

// workspace offsets (in floats)
#define OFF_X2   0                        // [TD][NB][PREN]
#define OFF_PE   (OFF_X2 + TD*NB*PREN)    // [NB][TE][ATT]
#define OFF_AWC  (OFF_PE + NB*TE*ATT)     // [NB][TE]
#define OFF_EN   (OFF_AWC + NB*TE)        // [NB][TE]
#define OFF_Q    (OFF_EN + NB*TE)         // [NB][ATT]
#define OFF_CTX  (OFF_Q + NB*ATT)         // [NB][EE]
#define OFF_H1   (OFF_CTX + NB*EE)        // [NB][HH]
#define OFF_H2   (OFF_H1 + NB*HH)         // [NB][HH]
#define OFF_BAR  (OFF_H2 + NB*HH)         // barrier flags, BAR_U32 uints
#define BAR_U32  16384

// bar u32 layout: flags 64B-strided, RMW-free
#define GO_G   4096                       // global go word
#define FL_L   4352                       // + bid*16 : local arrival flags
#define GO_L   8448                       // + grp*16 : local go words

// dynamic LDS: 12 rows x 768 (w_ih0 slice) + 12 rows x 1024 (w_ih1 slice)
#define LW0_F4   (12*192)
#define LW1_F4   (12*256)
#define DYN_BYTES ((LW0_F4 + LW1_F4) * 16)

#define SCOPE __HIP_MEMORY_SCOPE_AGENT

__device__ __forceinline__ float sigmf(float x) { return 1.0f / (1.0f + expf(-x)); }
__device__ __forceinline__ float dot4(float4 a, float4 b) {
  return a.x*b.x + a.y*b.y + a.z*b.z + a.w*b.w;
}
__device__ __forceinline__ float red32(float v) {
  v += __shfl_down(v, 16, 32); v += __shfl_down(v, 8, 32);
  v += __shfl_down(v, 4, 32);  v += __shfl_down(v, 2, 32);
  v += __shfl_down(v, 1, 32);
  return v;
}

// ---- RMW-free barriers: arrival flags + master-poll + broadcast go ----
__device__ __forceinline__ void gbar2(unsigned* bar, unsigned e) {
  __syncthreads();
  if (threadIdx.x == 0)
    __hip_atomic_store(bar + blockIdx.x * 16, e, __ATOMIC_RELEASE, SCOPE);
  if (blockIdx.x == 0) {
    if (threadIdx.x < 256) {
      while (__hip_atomic_load(bar + threadIdx.x * 16, __ATOMIC_ACQUIRE, SCOPE) < e)
        __builtin_amdgcn_s_sleep(1);
    }
    __syncthreads();
    if (threadIdx.x == 0)
      __hip_atomic_store(bar + GO_G, e, __ATOMIC_RELEASE, SCOPE);
  }
  if (threadIdx.x == 0) {
    while (__hip_atomic_load(bar + GO_G, __ATOMIC_ACQUIRE, SCOPE) < e)
      __builtin_amdgcn_s_sleep(1);
  }
  __syncthreads();
}

__device__ __forceinline__ void lbar2(unsigned* bar, unsigned e, int grp, int sub) {
  __syncthreads();
  if (threadIdx.x == 0)
    __hip_atomic_store(bar + FL_L + blockIdx.x * 16, e, __ATOMIC_RELEASE, SCOPE);
  if (sub == 0) {
    if (threadIdx.x < 16) {
      while (__hip_atomic_load(bar + FL_L + (threadIdx.x * 16 + grp) * 16,
                               __ATOMIC_ACQUIRE, SCOPE) < e)
        __builtin_amdgcn_s_sleep(1);
    }
    __syncthreads();
    if (threadIdx.x == 0)
      __hip_atomic_store(bar + GO_L + grp * 16, e, __ATOMIC_RELEASE, SCOPE);
  }
  if (threadIdx.x == 0) {
    while (__hip_atomic_load(bar + GO_L + grp * 16, __ATOMIC_ACQUIRE, SCOPE) < e)
      __builtin_amdgcn_s_sleep(1);
  }
  __syncthreads();
}

// ---------------- init ----------------
__global__ void k_init(float* __restrict__ ws) {
  const int tid = threadIdx.x;
  float* awc = ws + OFF_AWC;
  float* qv  = ws + OFF_Q;
  unsigned* bar = (unsigned*)(ws + OFF_BAR);
  for (int i = tid; i < NB*TE; i += 256) awc[i] = 0.0f;
  for (int i = tid; i < NB*ATT; i += 256) qv[i] = 0.0f;
  for (int i = tid; i < BAR_U32; i += 256) bar[i] = 0u;
}

// ---------------- prenet ----------------
__global__ void k_prenet(const float* __restrict__ mels,
                         const float* __restrict__ w1,
                         const float* __restrict__ w2,
                         float* __restrict__ x2) {
  const int t = blockIdx.x >> 4;
  const int b = blockIdx.x & 15;
  const int j = threadIdx.x;
  __shared__ float s_in[NMEL];
  __shared__ float s_x1[PREN];
  if (j < NMEL) s_in[j] = (t == 0) ? 0.0f : mels[(b*TD + (t-1))*NMEL + j];
  __syncthreads();
  float a1 = 0.0f;
  #pragma unroll 8
  for (int k = 0; k < NMEL; ++k) a1 += s_in[k] * w1[j*NMEL + k];
  s_x1[j] = fmaxf(a1, 0.0f);
  __syncthreads();
  float a2 = 0.0f;
  #pragma unroll 8
  for (int k = 0; k < PREN; ++k) a2 += s_x1[k] * w2[j*PREN + k];
  x2[(t*NB + b)*PREN + j] = fmaxf(a2, 0.0f);
}

// ---------------- processed encoder ----------------
__global__ void k_procenc(const float* __restrict__ enc,
                          const float* __restrict__ w,
                          float* __restrict__ pe) {
  const int bt = blockIdx.x;
  const int a = threadIdx.x;
  __shared__ float s_e[EE];
  for (int k = a; k < EE; k += 128) s_e[k] = enc[bt*EE + k];
  __syncthreads();
  float acc = 0.0f;
  #pragma unroll 8
  for (int k = 0; k < EE; ++k) acc += s_e[k] * w[a*EE + k];
  pe[bt*ATT + a] = acc;
}

// ---------------- main sequential decoder loop ----------------
__global__ void __launch_bounds__(512, 1) k_main(
    const float* __restrict__ enc,
    const float* __restrict__ lstm_proj_w,
    const float* __restrict__ loc_conv_w,
    const float* __restrict__ loc_conv_b,
    const float* __restrict__ loc_dense_w,
    const float* __restrict__ loc_dense_b,
    const float* __restrict__ e_w,
    const float* __restrict__ e_b,
    const float* __restrict__ w_ih0,
    const float* __restrict__ b_ih0,
    const float* __restrict__ b_hh0,
    const float* __restrict__ w_ih1,
    const float* __restrict__ b_ih1,
    const float* __restrict__ b_hh1,
    const float* __restrict__ proj_w,
    const float* __restrict__ proj_b,
    const float* __restrict__ stop_w,
    const float* __restrict__ stop_b,
    const int*   __restrict__ text_len,
    float* __restrict__ ws,
    float* __restrict__ out) {
  const int bid = blockIdx.x;   // 0..255
  const int tid = threadIdx.x;  // 0..511

  float* x2  = ws + OFF_X2;
  float* pe  = ws + OFF_PE;
  float* awc = ws + OFF_AWC;
  float* en  = ws + OFF_EN;
  float* qv  = ws + OFF_Q;
  float* ctx = ws + OFF_CTX;
  float* h1  = ws + OFF_H1;
  float* h2  = ws + OFF_H2;
  unsigned* bar = (unsigned*)(ws + OFF_BAR);

  __shared__ __align__(16) float s_ldw[NLOC*ATT];   // [c][a], f4-readable
  __shared__ __align__(16) float s_pe[16*ATT];      // this block's pe slice
  __shared__ float s_lcw[NLOC*33];                  // conv w [c][k] pad33
  __shared__ float s_lcb[NLOC];
  __shared__ __align__(16) float s_ldb[ATT];
  __shared__ __align__(16) float s_ew[ATT];
  __shared__ __align__(16) float s_q[ATT];
  __shared__ float s_awc[64];
  __shared__ float s_loc[16*33];
  __shared__ float s_red[16];
  __shared__ float s_aw[256];
  __shared__ __align__(16) float s_dec[HH+EE];
  __shared__ float s_b0[12], s_b1[12];
  extern __shared__ __align__(16) float dynlds[];
  float4* lw0 = (float4*)dynlds;
  float4* lw1 = ((float4*)dynlds) + LW0_F4;

  const int b_grp = bid & 15;   // batch this block serves in P1/P2/P5
  const int sub   = bid >> 4;   // 0..15 chunk within group
  const int h0    = bid * 4;    // this block's 4 h-outputs in P3/P4

  // ---- one-time staging ----
  for (int i = tid; i < NLOC*ATT; i += 512) {
    int c = i >> 7, a = i & 127;
    s_ldw[i] = loc_dense_w[a*NLOC + c];
  }
  for (int i = tid; i < 16*ATT; i += 512) {
    int tl = i >> 7, a = i & 127;
    s_pe[i] = pe[(b_grp*TE + sub*16 + tl)*ATT + a];
  }
  for (int i = tid; i < NLOC*33; i += 512) {
    int c = i / 33, k = i - 33*c;
    s_lcw[i] = (k < KWW) ? loc_conv_w[c*KWW + k] : 0.0f;
  }
  if (tid < NLOC) s_lcb[tid] = loc_conv_b[tid];
  if (tid >= 64 && tid < 64+ATT) s_ldb[tid-64] = loc_dense_b[tid-64];
  if (tid >= 256 && tid < 256+ATT) s_ew[tid-256] = e_w[tid-256];
  if (tid < 12) {
    int g = tid >> 2, h = tid & 3;
    int gr = (g == 0 ? 0 : (g == 1 ? 2048 : 3072)) + h0 + h;
    s_b0[tid] = b_ih0[gr] + b_hh0[gr];
    s_b1[tid] = b_ih1[gr] + b_hh1[gr];
  }
  {
    const float4* w0_4 = (const float4*)w_ih0;   // row stride 192 f4
    const float4* w1_4 = (const float4*)w_ih1;   // row stride 256 f4
    for (int i = tid; i < LW0_F4; i += 512) {
      int r = i / 192, c = i - r*192;
      int g = r >> 2, h = r & 3;
      int grow = (g == 0 ? 0 : (g == 1 ? 2048 : 3072)) + h0 + h;
      lw0[i] = w0_4[grow*192 + c];
    }
    for (int i = tid; i < LW1_F4; i += 512) {
      int r = i >> 8, c = i & 255;
      int g = r >> 2, h = r & 3;
      int grow = (g == 0 ? 0 : (g == 1 ? 2048 : 3072)) + h0 + h;
      lw1[i] = w1_4[grow*256 + c];
    }
  }
  const int   lenb = text_len[b_grp];
  const float eb0  = e_b[0];
  // register-cache conv taps for c = tid&31 (used in P1)
  float lcw_r[KWW];
  {
    const int c = tid & 31;
    #pragma unroll
    for (int k = 0; k < KWW; ++k) lcw_r[k] = loc_conv_w[c*KWW + k];
  }
  __syncthreads();

  unsigned eg = 0, el = 0;

  for (int t = 0; t < TD; ++t) {
    // ===== P1: energies for (b_grp, tt = sub*16 + tl) =====
    {
      const int tl = tid >> 5;   // 0..15
      const int j  = tid & 31;   // 0..31
      const int tt = sub*16 + tl;
      if (tid < ATT) s_q[tid] = qv[b_grp*ATT + tid];
      else if (tid < ATT + 64) {
        const int i = tid - ATT;
        const int g = sub*16 - PADW + i;
        s_awc[i] = (i < 46 && g >= 0 && g < TE) ? awc[b_grp*TE + g] : 0.0f;
      }
      __syncthreads();
      float cv = s_lcb[j];
      #pragma unroll
      for (int k = 0; k < KWW; ++k) cv += s_awc[tl + k] * lcw_r[k];
      s_loc[tl*33 + j] = cv;
      __syncthreads();
      float4 d4 = make_float4(0.f, 0.f, 0.f, 0.f);
      #pragma unroll 8
      for (int c = 0; c < NLOC; ++c) {
        const float lv = s_loc[tl*33 + c];
        const float4 w4 = ((const float4*)s_ldw)[c*32 + j];
        d4.x += lv*w4.x; d4.y += lv*w4.y; d4.z += lv*w4.z; d4.w += lv*w4.w;
      }
      const float4 q4  = ((const float4*)s_q)[j];
      const float4 db4 = ((const float4*)s_ldb)[j];
      const float4 p4  = ((const float4*)s_pe)[tl*32 + j];
      const float4 e4  = ((const float4*)s_ew)[j];
      float acc = tanhf(q4.x+db4.x+p4.x+d4.x)*e4.x
                + tanhf(q4.y+db4.y+p4.y+d4.y)*e4.y
                + tanhf(q4.z+db4.z+p4.z+d4.z)*e4.z
                + tanhf(q4.w+db4.w+p4.w+d4.w)*e4.w;
      acc = red32(acc);
      if (j == 0) {
        float evv = acc + eb0;
        if (tt >= lenb) evv = -1e9f;
        en[b_grp*TE + tt] = evv;
      }
    }
    lbar2(bar, ++el, b_grp, sub);
    // ===== P2: softmax + awc + ctx =====
    {
      float evv = 0.f, p = 0.f;
      if (tid < 256) {
        evv = en[b_grp*TE + tid];
        float m = evv;
        #pragma unroll
        for (int d = 32; d > 0; d >>= 1) m = fmaxf(m, __shfl_xor(m, d));
        if ((tid & 63) == 0) s_red[tid >> 6] = m;
      }
      __syncthreads();
      const float mx = fmaxf(fmaxf(s_red[0], s_red[1]), fmaxf(s_red[2], s_red[3]));
      if (tid < 256) {
        p = expf(evv - mx);
        float sm = p;
        #pragma unroll
        for (int d = 32; d > 0; d >>= 1) sm += __shfl_xor(sm, d);
        if ((tid & 63) == 0) s_red[8 + (tid >> 6)] = sm;
      }
      __syncthreads();
      const float inv = 1.0f / (s_red[8] + s_red[9] + s_red[10] + s_red[11]);
      if (tid < 256) {
        const float aw = p * inv;
        s_aw[tid] = aw;
        if (sub == 0) awc[b_grp*TE + tid] += aw;
      }
      __syncthreads();
      const int e4i = tid >> 6;   // 0..7
      const int ts  = tid & 63;
      const float4* enc4 = (const float4*)(enc + (size_t)b_grp*TE*EE);
      float4 a4 = make_float4(0.f, 0.f, 0.f, 0.f);
      #pragma unroll
      for (int i = 0; i < 4; ++i) {
        const int tt2 = ts + 64*i;
        const float awv = s_aw[tt2];
        const float4 ev4 = enc4[(size_t)tt2*(EE/4) + sub*8 + e4i];
        a4.x += awv*ev4.x; a4.y += awv*ev4.y; a4.z += awv*ev4.z; a4.w += awv*ev4.w;
      }
      #pragma unroll
      for (int d = 32; d > 0; d >>= 1) {
        a4.x += __shfl_down(a4.x, d);
        a4.y += __shfl_down(a4.y, d);
        a4.z += __shfl_down(a4.z, d);
        a4.w += __shfl_down(a4.w, d);
      }
      if (ts == 0) ((float4*)ctx)[b_grp*(EE/4) + sub*8 + e4i] = a4;
    }
    gbar2(bar, ++eg);
    // ===== P3: LSTM0 — block computes h = h0..h0+3 for all 16 batches =====
    {
      const int rq = tid >> 7;         // 0..3 : h within block
      const int bq = (tid >> 5) & 3;   // 0..3 : batch quad
      const int kc = tid & 31;
      float a0[4] = {0,0,0,0}, a1[4] = {0,0,0,0}, a2[4] = {0,0,0,0};
      const float4* x4p = (const float4*)(x2 + (size_t)(t*NB)*PREN);
      const float4* c4p = (const float4*)ctx;
      #pragma unroll
      for (int i = 0; i < 2; ++i) {               // x part: 64 f4
        const int kf = kc + 32*i;
        const float4 w0 = lw0[rq*192 + kf];
        const float4 w1 = lw0[(rq+4)*192 + kf];
        const float4 w2 = lw0[(rq+8)*192 + kf];
        #pragma unroll
        for (int bi = 0; bi < 4; ++bi) {
          const float4 xv = x4p[(bq*4+bi)*64 + kf];
          a0[bi] += dot4(xv, w0); a1[bi] += dot4(xv, w1); a2[bi] += dot4(xv, w2);
        }
      }
      #pragma unroll
      for (int i = 0; i < 4; ++i) {               // ctx part: 128 f4
        const int kf = kc + 32*i;
        const float4 w0 = lw0[rq*192 + 64 + kf];
        const float4 w1 = lw0[(rq+4)*192 + 64 + kf];
        const float4 w2 = lw0[(rq+8)*192 + 64 + kf];
        #pragma unroll
        for (int bi = 0; bi < 4; ++bi) {
          const float4 cvv = c4p[(bq*4+bi)*128 + kf];
          a0[bi] += dot4(cvv, w0); a1[bi] += dot4(cvv, w1); a2[bi] += dot4(cvv, w2);
        }
      }
      #pragma unroll
      for (int bi = 0; bi < 4; ++bi) {
        a0[bi] = red32(a0[bi]); a1[bi] = red32(a1[bi]); a2[bi] = red32(a2[bi]);
      }
      if (kc == 0) {
        #pragma unroll
        for (int bi = 0; bi < 4; ++bi) {
          const int b = bq*4 + bi;
          const float gi = a0[bi] + s_b0[rq];
          const float gg = a1[bi] + s_b0[4 + rq];
          const float go = a2[bi] + s_b0[8 + rq];
          const float c = sigmf(gi) * tanhf(gg);
          h1[b*HH + h0 + rq] = sigmf(go) * tanhf(c);
        }
      }
    }
    gbar2(bar, ++eg);
    // ===== P4: LSTM1 =====
    {
      const int rq = tid >> 7;
      const int bq = (tid >> 5) & 3;
      const int kc = tid & 31;
      float a0[4] = {0,0,0,0}, a1[4] = {0,0,0,0}, a2[4] = {0,0,0,0};
      const float4* h4p = (const float4*)h1;
      #pragma unroll
      for (int i = 0; i < 8; ++i) {               // 256 f4
        const int kf = kc + 32*i;
        const float4 w0 = lw1[rq*256 + kf];
        const float4 w1 = lw1[(rq+4)*256 + kf];
        const float4 w2 = lw1[(rq+8)*256 + kf];
        #pragma unroll
        for (int bi = 0; bi < 4; ++bi) {
          const float4 hv = h4p[(bq*4+bi)*256 + kf];
          a0[bi] += dot4(hv, w0); a1[bi] += dot4(hv, w1); a2[bi] += dot4(hv, w2);
        }
      }
      #pragma unroll
      for (int bi = 0; bi < 4; ++bi) {
        a0[bi] = red32(a0[bi]); a1[bi] = red32(a1[bi]); a2[bi] = red32(a2[bi]);
      }
      if (kc == 0) {
        #pragma unroll
        for (int bi = 0; bi < 4; ++bi) {
          const int b = bq*4 + bi;
          const float gi = a0[bi] + s_b1[rq];
          const float gg = a1[bi] + s_b1[4 + rq];
          const float go = a2[bi] + s_b1[8 + rq];
          const float c = sigmf(gi) * tanhf(gg);
          h2[b*HH + h0 + rq] = sigmf(go) * tanhf(c);
        }
      }
    }
    gbar2(bar, ++eg);
    // ===== P5: qv (sub<8) ; mel/stop (sub>=8) =====
    {
      for (int i = tid; i < HH + EE; i += 512)
        s_dec[i] = (i < HH) ? h2[b_grp*HH + i] : ctx[b_grp*EE + (i - HH)];
      __syncthreads();
      const int ol = tid >> 5;   // 0..15
      const int kc = tid & 31;
      const float4* s4 = (const float4*)s_dec;
      if (sub < 8) {
        const int a = sub*16 + ol;
        const float4* w4 = (const float4*)(lstm_proj_w + (size_t)a*HH);
        float acc = 0.0f;
        #pragma unroll
        for (int i = 0; i < 8; ++i) {
          const int kf = kc + 32*i;
          acc += dot4(s4[kf], w4[kf]);
        }
        acc = red32(acc);
        if (kc == 0) qv[b_grp*ATT + a] = acc;
      } else {
        const int m = (sub - 8)*11 + ol;
        if (ol < 11 && m < 81) {
          const float* wrow = (m < NMEL) ? (proj_w + (size_t)m*(HH+EE)) : stop_w;
          const float4* w4 = (const float4*)wrow;
          float acc = 0.0f;
          #pragma unroll
          for (int i = 0; i < 12; ++i) {
            const int kf = kc + 32*i;
            acc += dot4(s4[kf], w4[kf]);
          }
          acc = red32(acc);
          if (kc == 0) {
            if (m < NMEL) out[(b_grp*TD + t)*NMEL + m] = acc + proj_b[m];
            else          out[NB*TD*NMEL + b_grp*TD + t] = acc + stop_b[0];
          }
        }
      }
    }
    lbar2(bar, ++el, b_grp, sub);
  }
}

extern "C" void kernel_launch(void* const* d_in, const int* in_sizes, int n_in,
                              void* d_out, int out_size, void* d_ws, size_t ws_size,
                              hipStream_t stream) {
  (void)in_sizes; (void)n_in; (void)out_size; (void)ws_size;
  const float* enc         = (const float*)d_in[0];
  const float* mels        = (const float*)d_in[1];
  const float* enc_proj_w  = (const float*)d_in[2];
  const float* lstm_proj_w = (const float*)d_in[3];
  const float* loc_conv_w  = (const float*)d_in[4];
  const float* loc_conv_b  = (const float*)d_in[5];
  const float* loc_dense_w = (const float*)d_in[6];
  const float* loc_dense_b = (const float*)d_in[7];
  const float* e_w         = (const float*)d_in[8];
  const float* e_b         = (const float*)d_in[9];
  const float* prenet1_w   = (const float*)d_in[10];
  const float* prenet2_w   = (const float*)d_in[11];
  const float* w_ih0       = (const float*)d_in[12];
  const float* b_ih0       = (const float*)d_in[14];
  const float* b_hh0       = (const float*)d_in[15];
  const float* w_ih1       = (const float*)d_in[16];
  const float* b_ih1       = (const float*)d_in[18];
  const float* b_hh1       = (const float*)d_in[19];
  const float* proj_w      = (const float*)d_in[20];
  const float* proj_b      = (const float*)d_in[21];
  const float* stop_w      = (const float*)d_in[22];
  const float* stop_b      = (const float*)d_in[23];
  const int*   text_len    = (const int*)d_in[24];
  float* ws  = (float*)d_ws;
  float* out = (float*)d_out;

  static int attr_set = 0;
  if (!attr_set) {
    hipFuncSetAttribute((const void*)k_main,
                        hipFuncAttributeMaxDynamicSharedMemorySize, DYN_BYTES);
    attr_set = 1;
  }

  k_init<<<dim3(1), dim3(256), 0, stream>>>(ws);
  k_prenet<<<dim3(TD*NB), dim3(256), 0, stream>>>(mels, prenet1_w, prenet2_w, ws + OFF_X2);
  k_procenc<<<dim3(NB*TE), dim3(128), 0, stream>>>(enc, enc_proj_w, ws + OFF_PE);

  k_main<<<dim3(256), dim3(512), DYN_BYTES, stream>>>(
      enc, lstm_proj_w, loc_conv_w, loc_conv_b, loc_dense_w, loc_dense_b,
      e_w, e_b, w_ih0, b_ih0, b_hh0, w_ih1, b_ih1, b_hh1,
      proj_w, proj_b, stop_w, stop_b, text_len, ws, out);
}

// Round 5
// 4796.288 us; speedup vs baseline: 5.6810x; 5.6810x over previous
//
#include <hip/hip_runtime.h>
#include <math.h>

#define NB   16    // batch
#define TE   256   // T_ENC
#define TD   200   // T_DEC
#define EE   512   // encoder dim
#define ATT  128
#define PREN 256
#define HH   1024
#define NMEL 80
#define NLOC 32
#define KWW  31
#define PADW 15

// workspace offsets (in floats)
#define OFF_X2   0                        // [TD][NB][PREN]
#define OFF_PE   (OFF_X2 + TD*NB*PREN)    // [NB][TE][ATT]
#define OFF_AWC  (OFF_PE + NB*TE*ATT)     // [NB][TE]
#define OFF_EN   (OFF_AWC + NB*TE)        // [NB][TE]
#define OFF_Q    (OFF_EN + NB*TE)         // [NB][ATT]
#define OFF_CTX  (OFF_Q + NB*ATT)         // [NB][EE]
#define OFF_H1   (OFF_CTX + NB*EE)        // [NB][HH]
#define OFF_H2   (OFF_H1 + NB*HH)         // [NB][HH]
#define OFF_BAR  (OFF_H2 + NB*HH)         // barrier flags, BAR_U32 uints
#define BAR_U32  16384

// flag layout (uints, 64B stride): private lines, no sharing
#define ARR_G  0        // + bid*16 : global arrival
#define GOPRI  4096     // + bid*16 : global per-block go
#define ARR_L  8192     // + bid*16 : local arrival
#define GO_L2  12288    // + bid*16 : local per-block go

// dynamic LDS: 12 rows x 768 (w_ih0 slice) + 12 rows x 1024 (w_ih1 slice)
#define LW0_F4   (12*192)
#define LW1_F4   (12*256)
#define DYN_BYTES ((LW0_F4 + LW1_F4) * 16)

typedef float f4 __attribute__((ext_vector_type(4)));

__device__ __forceinline__ float sigmf(float x) { return 1.0f / (1.0f + expf(-x)); }
__device__ __forceinline__ float dot4(f4 a, f4 b) {
  return a.x*b.x + a.y*b.y + a.z*b.z + a.w*b.w;
}
__device__ __forceinline__ float red32(float v) {
  v += __shfl_down(v, 16, 32); v += __shfl_down(v, 8, 32);
  v += __shfl_down(v, 4, 32);  v += __shfl_down(v, 2, 32);
  v += __shfl_down(v, 1, 32);
  return v;
}
__device__ __forceinline__ float red16(float v) {
  v += __shfl_down(v, 8, 16); v += __shfl_down(v, 4, 16);
  v += __shfl_down(v, 2, 16); v += __shfl_down(v, 1, 16);
  return v;
}

// ---- LLC-coherent (L1+L2 bypass) accessors: no fences, no cache maintenance ----
__device__ __forceinline__ unsigned ld_cg_u32(const unsigned* p) {
  unsigned r;
  asm volatile("global_load_dword %0, %1, off sc0 sc1\n\ts_waitcnt vmcnt(0)"
               : "=v"(r) : "v"(p) : "memory");
  return r;
}
__device__ __forceinline__ void st_cg_u32(unsigned* p, unsigned v) {
  asm volatile("global_store_dword %0, %1, off sc0 sc1" :: "v"(p), "v"(v) : "memory");
}
__device__ __forceinline__ float ld_cg_f32(const float* p) {
  float r;
  asm volatile("global_load_dword %0, %1, off sc0 sc1\n\ts_waitcnt vmcnt(0)"
               : "=v"(r) : "v"(p) : "memory");
  return r;
}
__device__ __forceinline__ void st_cg_f32(float* p, float v) {
  asm volatile("global_store_dword %0, %1, off sc0 sc1" :: "v"(p), "v"(v) : "memory");
}
__device__ __forceinline__ f4 ld_cg_f4(const f4* p) {
  f4 r;
  asm volatile("global_load_dwordx4 %0, %1, off sc0 sc1\n\ts_waitcnt vmcnt(0)"
               : "=v"(r) : "v"(p) : "memory");
  return r;
}
__device__ __forceinline__ void st_cg_f4(f4* p, f4 v) {
  asm volatile("global_store_dwordx4 %0, %1, off sc0 sc1" :: "v"(p), "v"(v) : "memory");
}
// 4 loads in flight, single wait
__device__ __forceinline__ void ld4_cg(f4& r0, f4& r1, f4& r2, f4& r3,
                                       const f4* a0, const f4* a1,
                                       const f4* a2, const f4* a3) {
  asm volatile(
    "global_load_dwordx4 %0, %4, off sc0 sc1\n\t"
    "global_load_dwordx4 %1, %5, off sc0 sc1\n\t"
    "global_load_dwordx4 %2, %6, off sc0 sc1\n\t"
    "global_load_dwordx4 %3, %7, off sc0 sc1\n\t"
    "s_waitcnt vmcnt(0)"
    : "=&v"(r0), "=&v"(r1), "=&v"(r2), "=&v"(r3)
    : "v"(a0), "v"(a1), "v"(a2), "v"(a3)
    : "memory");
}

// ---- barriers: private arrival lines + master poll + private go lines ----
// producer ordering: __syncthreads() drains each wave's vmcnt(0) before
// s_barrier, so all sc0sc1 data stores are LLC-visible before the arrival
// flag store. consumer ordering: go-poll completes before post-barrier loads.
__device__ __forceinline__ void gbar(unsigned* bar, unsigned e) {
  __syncthreads();
  if (threadIdx.x == 0) st_cg_u32(bar + ARR_G + blockIdx.x * 16, e);
  if (blockIdx.x == 0) {
    if (threadIdx.x < 256) {
      while (ld_cg_u32(bar + ARR_G + threadIdx.x * 16) < e)
        __builtin_amdgcn_s_sleep(2);
    }
    __syncthreads();
    if (threadIdx.x < 256) st_cg_u32(bar + GOPRI + threadIdx.x * 16, e);
  }
  if (threadIdx.x == 0) {
    while (ld_cg_u32(bar + GOPRI + blockIdx.x * 16) < e)
      __builtin_amdgcn_s_sleep(2);
  }
  __syncthreads();
}

__device__ __forceinline__ void lbar(unsigned* bar, unsigned e, int b_grp, int sub) {
  __syncthreads();
  if (threadIdx.x == 0) st_cg_u32(bar + ARR_L + blockIdx.x * 16, e);
  if (sub == 0) {
    if (threadIdx.x < 16) {
      while (ld_cg_u32(bar + ARR_L + (threadIdx.x * 16 + b_grp) * 16) < e)
        __builtin_amdgcn_s_sleep(2);
    }
    __syncthreads();
    if (threadIdx.x < 16) st_cg_u32(bar + GO_L2 + (threadIdx.x * 16 + b_grp) * 16, e);
  }
  if (threadIdx.x == 0) {
    while (ld_cg_u32(bar + GO_L2 + blockIdx.x * 16) < e)
      __builtin_amdgcn_s_sleep(2);
  }
  __syncthreads();
}

// ---------------- init (cg stores so k_main's LLC reads see them) ----------------
__global__ void k_init(float* __restrict__ ws) {
  const int tid = threadIdx.x;
  float* awc = ws + OFF_AWC;
  float* qv  = ws + OFF_Q;
  unsigned* bar = (unsigned*)(ws + OFF_BAR);
  for (int i = tid; i < NB*TE; i += 256) st_cg_f32(awc + i, 0.0f);
  for (int i = tid; i < NB*ATT; i += 256) st_cg_f32(qv + i, 0.0f);
  for (int i = tid; i < BAR_U32; i += 256) st_cg_u32(bar + i, 0u);
}

// ---------------- prenet ----------------
__global__ void k_prenet(const float* __restrict__ mels,
                         const float* __restrict__ w1,
                         const float* __restrict__ w2,
                         float* __restrict__ x2) {
  const int t = blockIdx.x >> 4;
  const int b = blockIdx.x & 15;
  const int j = threadIdx.x;
  __shared__ float s_in[NMEL];
  __shared__ float s_x1[PREN];
  if (j < NMEL) s_in[j] = (t == 0) ? 0.0f : mels[(b*TD + (t-1))*NMEL + j];
  __syncthreads();
  float a1 = 0.0f;
  #pragma unroll 8
  for (int k = 0; k < NMEL; ++k) a1 += s_in[k] * w1[j*NMEL + k];
  s_x1[j] = fmaxf(a1, 0.0f);
  __syncthreads();
  float a2 = 0.0f;
  #pragma unroll 8
  for (int k = 0; k < PREN; ++k) a2 += s_x1[k] * w2[j*PREN + k];
  x2[(t*NB + b)*PREN + j] = fmaxf(a2, 0.0f);
}

// ---------------- processed encoder ----------------
__global__ void k_procenc(const float* __restrict__ enc,
                          const float* __restrict__ w,
                          float* __restrict__ pe) {
  const int bt = blockIdx.x;
  const int a = threadIdx.x;
  __shared__ float s_e[EE];
  for (int k = a; k < EE; k += 128) s_e[k] = enc[bt*EE + k];
  __syncthreads();
  float acc = 0.0f;
  #pragma unroll 8
  for (int k = 0; k < EE; ++k) acc += s_e[k] * w[a*EE + k];
  pe[bt*ATT + a] = acc;
}

// ---------------- main sequential decoder loop ----------------
__global__ void __launch_bounds__(512, 1) k_main(
    const float* __restrict__ enc,
    const float* __restrict__ lstm_proj_w,
    const float* __restrict__ loc_conv_w,
    const float* __restrict__ loc_conv_b,
    const float* __restrict__ loc_dense_w,
    const float* __restrict__ loc_dense_b,
    const float* __restrict__ e_w,
    const float* __restrict__ e_b,
    const float* __restrict__ w_ih0,
    const float* __restrict__ b_ih0,
    const float* __restrict__ b_hh0,
    const float* __restrict__ w_ih1,
    const float* __restrict__ b_ih1,
    const float* __restrict__ b_hh1,
    const float* __restrict__ proj_w,
    const float* __restrict__ proj_b,
    const float* __restrict__ stop_w,
    const float* __restrict__ stop_b,
    const int*   __restrict__ text_len,
    float* __restrict__ ws,
    float* __restrict__ out) {
  const int bid = blockIdx.x;   // 0..255
  const int tid = threadIdx.x;  // 0..511

  float* x2  = ws + OFF_X2;
  float* pe  = ws + OFF_PE;
  float* awc = ws + OFF_AWC;
  float* en  = ws + OFF_EN;
  float* qv  = ws + OFF_Q;
  float* ctx = ws + OFF_CTX;
  float* h1  = ws + OFF_H1;
  float* h2  = ws + OFF_H2;
  unsigned* bar = (unsigned*)(ws + OFF_BAR);

  __shared__ __align__(16) float s_ldw[NLOC*ATT];   // loc_dense_w^T [c][a]
  __shared__ __align__(16) float s_pe[16*ATT];      // this block's pe slice
  __shared__ float s_lcb[NLOC];
  __shared__ __align__(16) float s_ldb[ATT];
  __shared__ __align__(16) float s_ew[ATT];
  __shared__ __align__(16) float s_q[ATT];
  __shared__ float s_awc[64];
  __shared__ float s_loc[16*33];
  __shared__ float s_red[16];
  __shared__ float s_aw[256];
  __shared__ __align__(16) float s_dec[HH+EE];      // P5 staging; P3/P4 gate bounce
  __shared__ float s_b0[12], s_b1[12];
  extern __shared__ __align__(16) float dynlds[];
  f4* lw0 = (f4*)dynlds;
  f4* lw1 = ((f4*)dynlds) + LW0_F4;

  const int b_grp = bid & 15;   // batch this block serves in P1/P2/P5
  const int sub   = bid >> 4;   // 0..15 chunk within group
  const int h0    = bid * 4;    // this block's 4 h-outputs in P3/P4

  // ---- one-time staging (read-only inputs: plain cached loads) ----
  for (int i = tid; i < NLOC*ATT; i += 512) {
    int c = i >> 7, a = i & 127;
    s_ldw[i] = loc_dense_w[a*NLOC + c];
  }
  for (int i = tid; i < 16*ATT; i += 512) {
    int tl = i >> 7, a = i & 127;
    s_pe[i] = pe[(b_grp*TE + sub*16 + tl)*ATT + a];
  }
  if (tid < NLOC) s_lcb[tid] = loc_conv_b[tid];
  if (tid >= 64 && tid < 64+ATT) s_ldb[tid-64] = loc_dense_b[tid-64];
  if (tid >= 256 && tid < 256+ATT) s_ew[tid-256] = e_w[tid-256];
  if (tid < 12) {
    int g = tid >> 2, h = tid & 3;
    int gr = (g == 0 ? 0 : (g == 1 ? 2048 : 3072)) + h0 + h;
    s_b0[tid] = b_ih0[gr] + b_hh0[gr];
    s_b1[tid] = b_ih1[gr] + b_hh1[gr];
  }
  {
    const f4* w0_4 = (const f4*)w_ih0;   // row stride 192 f4
    const f4* w1_4 = (const f4*)w_ih1;   // row stride 256 f4
    for (int i = tid; i < LW0_F4; i += 512) {
      int r = i / 192, c = i - r*192;
      int g = r >> 2, h = r & 3;
      int grow = (g == 0 ? 0 : (g == 1 ? 2048 : 3072)) + h0 + h;
      lw0[i] = w0_4[grow*192 + c];
    }
    for (int i = tid; i < LW1_F4; i += 512) {
      int r = i >> 8, c = i & 255;
      int g = r >> 2, h = r & 3;
      int grow = (g == 0 ? 0 : (g == 1 ? 2048 : 3072)) + h0 + h;
      lw1[i] = w1_4[grow*256 + c];
    }
  }
  const int   lenb = text_len[b_grp];
  const float eb0  = e_b[0];
  float lcw_r[KWW];                    // conv taps for c = tid&31
  {
    const int c = tid & 31;
    #pragma unroll
    for (int k = 0; k < KWW; ++k) lcw_r[k] = loc_conv_w[c*KWW + k];
  }
  __syncthreads();

  unsigned eg = 0, el = 0;
  gbar(bar, ++eg);   // k_init flags/awc/qv at LLC; x2/pe via stream order

  for (int t = 0; t < TD; ++t) {
    // ===== P1: energies for (b_grp, tt = sub*16 + tl) =====
    {
      const int tl = tid >> 5;   // 0..15
      const int j  = tid & 31;   // 0..31
      const int tt = sub*16 + tl;
      if (tid < ATT) s_q[tid] = ld_cg_f32(qv + b_grp*ATT + tid);
      else if (tid < ATT + 64) {
        const int i = tid - ATT;
        const int g = sub*16 - PADW + i;
        s_awc[i] = (i < 46 && g >= 0 && g < TE) ? ld_cg_f32(awc + b_grp*TE + g)
                                                : 0.0f;
      }
      __syncthreads();
      float cv = s_lcb[j];
      #pragma unroll
      for (int k = 0; k < KWW; ++k) cv += s_awc[tl + k] * lcw_r[k];
      s_loc[tl*33 + j] = cv;
      __syncthreads();
      f4 d4 = (f4){0.f, 0.f, 0.f, 0.f};
      #pragma unroll 8
      for (int c = 0; c < NLOC; ++c) {
        const float lv = s_loc[tl*33 + c];
        const f4 w4 = ((const f4*)s_ldw)[c*32 + j];
        d4.x += lv*w4.x; d4.y += lv*w4.y; d4.z += lv*w4.z; d4.w += lv*w4.w;
      }
      const f4 q4  = ((const f4*)s_q)[j];
      const f4 db4 = ((const f4*)s_ldb)[j];
      const f4 p4  = ((const f4*)s_pe)[tl*32 + j];
      const f4 e4  = ((const f4*)s_ew)[j];
      float acc = tanhf(q4.x+db4.x+p4.x+d4.x)*e4.x
                + tanhf(q4.y+db4.y+p4.y+d4.y)*e4.y
                + tanhf(q4.z+db4.z+p4.z+d4.z)*e4.z
                + tanhf(q4.w+db4.w+p4.w+d4.w)*e4.w;
      acc = red32(acc);
      if (j == 0) {
        float evv = acc + eb0;
        if (tt >= lenb) evv = -1e9f;
        st_cg_f32(en + b_grp*TE + tt, evv);
      }
    }
    lbar(bar, ++el, b_grp, sub);
    // ===== P2: softmax (redundant per sub) + awc + ctx =====
    {
      float evv = 0.f, p = 0.f;
      if (tid < 256) {
        evv = ld_cg_f32(en + b_grp*TE + tid);
        float m = evv;
        #pragma unroll
        for (int d = 32; d > 0; d >>= 1) m = fmaxf(m, __shfl_xor(m, d));
        if ((tid & 63) == 0) s_red[tid >> 6] = m;
      }
      __syncthreads();
      const float mx = fmaxf(fmaxf(s_red[0], s_red[1]), fmaxf(s_red[2], s_red[3]));
      if (tid < 256) {
        p = expf(evv - mx);
        float sm = p;
        #pragma unroll
        for (int d = 32; d > 0; d >>= 1) sm += __shfl_xor(sm, d);
        if ((tid & 63) == 0) s_red[8 + (tid >> 6)] = sm;
      }
      __syncthreads();
      const float inv = 1.0f / (s_red[8] + s_red[9] + s_red[10] + s_red[11]);
      if (tid < 256) {
        const float aw = p * inv;
        s_aw[tid] = aw;
        if (sub == 0) {
          const float old = ld_cg_f32(awc + b_grp*TE + tid);
          st_cg_f32(awc + b_grp*TE + tid, old + aw);
        }
      }
      __syncthreads();
      const int e4i = tid >> 6;   // 0..7
      const int ts  = tid & 63;
      const f4* enc4 = (const f4*)(enc + (size_t)b_grp*TE*EE);
      f4 a4 = (f4){0.f, 0.f, 0.f, 0.f};
      #pragma unroll
      for (int i = 0; i < 4; ++i) {
        const int tt2 = ts + 64*i;
        const float awv = s_aw[tt2];
        const f4 ev4 = enc4[(size_t)tt2*(EE/4) + sub*8 + e4i];
        a4.x += awv*ev4.x; a4.y += awv*ev4.y; a4.z += awv*ev4.z; a4.w += awv*ev4.w;
      }
      #pragma unroll
      for (int d = 32; d > 0; d >>= 1) {
        a4.x += __shfl_down(a4.x, d);
        a4.y += __shfl_down(a4.y, d);
        a4.z += __shfl_down(a4.z, d);
        a4.w += __shfl_down(a4.w, d);
      }
      if (ts == 0) st_cg_f4((f4*)ctx + b_grp*(EE/4) + sub*8 + e4i, a4);
    }
    gbar(bar, ++eg);
    // ===== P3: LSTM0 — rows h0..h0+3, all 16 batches; (rq2,b,kc) mapping =====
    {
      const int rq2 = tid >> 8;        // 0..1 -> rows rq2*6..+5
      const int b   = (tid >> 4) & 15;
      const int kc  = tid & 15;
      const int R0  = rq2 * 6;
      float acc[6] = {0.f,0.f,0.f,0.f,0.f,0.f};
      const f4* x4p = (const f4*)(x2 + (size_t)(t*NB + b)*PREN);  // plain (RO)
      const f4* c4p = (const f4*)(ctx + b*EE);                    // cg
      #pragma unroll
      for (int i = 0; i < 4; ++i) {    // x part: 64 f4
        const int kf = kc + 16*i;
        const f4 xv = x4p[kf];
        #pragma unroll
        for (int r = 0; r < 6; ++r) acc[r] += dot4(xv, lw0[(R0+r)*192 + kf]);
      }
      #pragma unroll
      for (int half = 0; half < 2; ++half) {  // ctx part: 128 f4
        f4 cv0, cv1, cv2, cv3;
        const int k0 = kc + 64*half;
        ld4_cg(cv0, cv1, cv2, cv3, c4p+k0, c4p+k0+16, c4p+k0+32, c4p+k0+48);
        #pragma unroll
        for (int r = 0; r < 6; ++r) {
          acc[r] += dot4(cv0, lw0[(R0+r)*192 + 64 + k0]);
          acc[r] += dot4(cv1, lw0[(R0+r)*192 + 64 + k0 + 16]);
          acc[r] += dot4(cv2, lw0[(R0+r)*192 + 64 + k0 + 32]);
          acc[r] += dot4(cv3, lw0[(R0+r)*192 + 64 + k0 + 48]);
        }
      }
      #pragma unroll
      for (int r = 0; r < 6; ++r) acc[r] = red16(acc[r]);
      if (kc == 0) {
        #pragma unroll
        for (int r = 0; r < 6; ++r) s_dec[(R0 + r)*16 + b] = acc[r];
      }
      __syncthreads();
      if (tid < 64) {
        const int h = tid >> 4, b2 = tid & 15;
        const float gi = s_dec[h*16 + b2]     + s_b0[h];
        const float gg = s_dec[(4+h)*16 + b2] + s_b0[4+h];
        const float go = s_dec[(8+h)*16 + b2] + s_b0[8+h];
        const float c = sigmf(gi) * tanhf(gg);
        st_cg_f32(h1 + b2*HH + h0 + h, sigmf(go) * tanhf(c));
      }
    }
    gbar(bar, ++eg);
    // ===== P4: LSTM1 =====
    {
      const int rq2 = tid >> 8;
      const int b   = (tid >> 4) & 15;
      const int kc  = tid & 15;
      const int R0  = rq2 * 6;
      float acc[6] = {0.f,0.f,0.f,0.f,0.f,0.f};
      const f4* h4p = (const f4*)(h1 + b*HH);                     // cg
      #pragma unroll
      for (int q = 0; q < 4; ++q) {    // 256 f4
        f4 hv0, hv1, hv2, hv3;
        const int k0 = kc + 64*q;
        ld4_cg(hv0, hv1, hv2, hv3, h4p+k0, h4p+k0+16, h4p+k0+32, h4p+k0+48);
        #pragma unroll
        for (int r = 0; r < 6; ++r) {
          acc[r] += dot4(hv0, lw1[(R0+r)*256 + k0]);
          acc[r] += dot4(hv1, lw1[(R0+r)*256 + k0 + 16]);
          acc[r] += dot4(hv2, lw1[(R0+r)*256 + k0 + 32]);
          acc[r] += dot4(hv3, lw1[(R0+r)*256 + k0 + 48]);
        }
      }
      #pragma unroll
      for (int r = 0; r < 6; ++r) acc[r] = red16(acc[r]);
      if (kc == 0) {
        #pragma unroll
        for (int r = 0; r < 6; ++r) s_dec[(R0 + r)*16 + b] = acc[r];
      }
      __syncthreads();
      if (tid < 64) {
        const int h = tid >> 4, b2 = tid & 15;
        const float gi = s_dec[h*16 + b2]     + s_b1[h];
        const float gg = s_dec[(4+h)*16 + b2] + s_b1[4+h];
        const float go = s_dec[(8+h)*16 + b2] + s_b1[8+h];
        const float c = sigmf(gi) * tanhf(gg);
        st_cg_f32(h2 + b2*HH + h0 + h, sigmf(go) * tanhf(c));
      }
    }
    gbar(bar, ++eg);
    // ===== P5: qv (sub<8) ; mel/stop (sub>=8) =====
    {
      if (tid < 256)
        ((f4*)s_dec)[tid] = ld_cg_f4((const f4*)(h2 + b_grp*HH) + tid);
      else if (tid < 384)
        ((f4*)s_dec)[tid] = ld_cg_f4((const f4*)(ctx + b_grp*EE) + (tid - 256));
      __syncthreads();
      const int ol = tid >> 5;   // 0..15
      const int kc = tid & 31;
      const f4* s4 = (const f4*)s_dec;
      if (sub < 8) {
        const int a = sub*16 + ol;
        const f4* w4 = (const f4*)(lstm_proj_w + (size_t)a*HH);   // plain (RO)
        float acc = 0.0f;
        #pragma unroll
        for (int i = 0; i < 8; ++i) {
          const int kf = kc + 32*i;
          acc += dot4(s4[kf], w4[kf]);
        }
        acc = red32(acc);
        if (kc == 0) st_cg_f32(qv + b_grp*ATT + a, acc);
      } else {
        const int m = (sub - 8)*11 + ol;
        if (ol < 11 && m < 81) {
          const float* wrow = (m < NMEL) ? (proj_w + (size_t)m*(HH+EE)) : stop_w;
          const f4* w4 = (const f4*)wrow;                         // plain (RO)
          float acc = 0.0f;
          #pragma unroll
          for (int i = 0; i < 12; ++i) {
            const int kf = kc + 32*i;
            acc += dot4(s4[kf], w4[kf]);
          }
          acc = red32(acc);
          if (kc == 0) {
            if (m < NMEL) out[(b_grp*TD + t)*NMEL + m] = acc + proj_b[m];
            else          out[NB*TD*NMEL + b_grp*TD + t] = acc + stop_b[0];
          }
        }
      }
    }
    lbar(bar, ++el, b_grp, sub);
  }
}

extern "C" void kernel_launch(void* const* d_in, const int* in_sizes, int n_in,
                              void* d_out, int out_size, void* d_ws, size_t ws_size,
                              hipStream_t stream) {
  (void)in_sizes; (void)n_in; (void)out_size; (void)ws_size;
  const float* enc         = (const float*)d_in[0];
  const float* mels        = (const float*)d_in[1];
  const float* enc_proj_w  = (const float*)d_in[2];
  const float* lstm_proj_w = (const float*)d_in[3];
  const float* loc_conv_w  = (const float*)d_in[4];
  const float* loc_conv_b  = (const float*)d_in[5];
  const float* loc_dense_w = (const float*)d_in[6];
  const float* loc_dense_b = (const float*)d_in[7];
  const float* e_w         = (const float*)d_in[8];
  const float* e_b         = (const float*)d_in[9];
  const float* prenet1_w   = (const float*)d_in[10];
  const float* prenet2_w   = (const float*)d_in[11];
  const float* w_ih0       = (const float*)d_in[12];
  const float* b_ih0       = (const float*)d_in[14];
  const float* b_hh0       = (const float*)d_in[15];
  const float* w_ih1       = (const float*)d_in[16];
  const float* b_ih1       = (const float*)d_in[18];
  const float* b_hh1       = (const float*)d_in[19];
  const float* proj_w      = (const float*)d_in[20];
  const float* proj_b      = (const float*)d_in[21];
  const float* stop_w      = (const float*)d_in[22];
  const float* stop_b      = (const float*)d_in[23];
  const int*   text_len    = (const int*)d_in[24];
  float* ws  = (float*)d_ws;
  float* out = (float*)d_out;

  static int attr_set = 0;
  if (!attr_set) {
    hipFuncSetAttribute((const void*)k_main,
                        hipFuncAttributeMaxDynamicSharedMemorySize, DYN_BYTES);
    attr_set = 1;
  }

  k_init<<<dim3(1), dim3(256), 0, stream>>>(ws);
  k_prenet<<<dim3(TD*NB), dim3(256), 0, stream>>>(mels, prenet1_w, prenet2_w, ws + OFF_X2);
  k_procenc<<<dim3(NB*TE), dim3(128), 0, stream>>>(enc, enc_proj_w, ws + OFF_PE);

  k_main<<<dim3(256), dim3(512), DYN_BYTES, stream>>>(
      enc, lstm_proj_w, loc_conv_w, loc_conv_b, loc_dense_w, loc_dense_b,
      e_w, e_b, w_ih0, b_ih0, b_hh0, w_ih1, b_ih1, b_hh1,
      proj_w, proj_b, stop_w, stop_b, text_len, ws, out);
}

// Round 6
// 4471.128 us; speedup vs baseline: 6.0941x; 1.0727x over previous
//
#include <hip/hip_runtime.h>
#include <math.h>

#define NB   16    // batch
#define TE   256   // T_ENC
#define TD   200   // T_DEC
#define EE   512   // encoder dim
#define ATT  128
#define PREN 256
#define HH   1024
#define NMEL 80
#define NLOC 32
#define KWW  31
#define PADW 15

// workspace offsets (in floats)
#define OFF_X2   0                        // [TD][NB][PREN]
#define OFF_PE   (OFF_X2 + TD*NB*PREN)    // [NB][TE][ATT]
#define OFF_AWC  (OFF_PE + NB*TE*ATT)     // [NB][TE]
#define OFF_EN   (OFF_AWC + NB*TE)        // [NB][TE]
#define OFF_Q    (OFF_EN + NB*TE)         // [NB][ATT]
#define OFF_CTX  (OFF_Q + NB*ATT)         // [NB][EE]
#define OFF_H1   (OFF_CTX + NB*EE)        // [NB][HH]
#define OFF_H2   (OFF_H1 + NB*HH)         // [NB][HH]
#define OFF_BAR  (OFF_H2 + NB*HH)         // barrier flags
#define BAR_U32  8192

// flag lines (uints, 64B stride, all private per block)
#define ARR_G  0        // + bid*16 : global arrival epoch
#define ARR_L  4096     // + bid*16 : local (batch-group) arrival epoch

// dynamic LDS: 12 rows x 768 (w_ih0 slice) + 12 rows x 1024 (w_ih1 slice)
#define LW0_F4   (12*192)
#define LW1_F4   (12*256)
#define DYN_BYTES ((LW0_F4 + LW1_F4) * 16)

typedef float f4 __attribute__((ext_vector_type(4)));

__device__ __forceinline__ float sigmf(float x) { return 1.0f / (1.0f + expf(-x)); }
__device__ __forceinline__ float dot4(f4 a, f4 b) {
  return a.x*b.x + a.y*b.y + a.z*b.z + a.w*b.w;
}
__device__ __forceinline__ float red32(float v) {
  v += __shfl_down(v, 16, 32); v += __shfl_down(v, 8, 32);
  v += __shfl_down(v, 4, 32);  v += __shfl_down(v, 2, 32);
  v += __shfl_down(v, 1, 32);
  return v;
}

// ---- LLC-coherent (L1+L2 bypass) accessors ----
__device__ __forceinline__ unsigned ld_cg_u32(const unsigned* p) {
  unsigned r;
  asm volatile("global_load_dword %0, %1, off sc0 sc1\n\ts_waitcnt vmcnt(0)"
               : "=v"(r) : "v"(p) : "memory");
  return r;
}
__device__ __forceinline__ void st_cg_u32(unsigned* p, unsigned v) {
  asm volatile("global_store_dword %0, %1, off sc0 sc1" :: "v"(p), "v"(v) : "memory");
}
__device__ __forceinline__ float ld_cg_f32(const float* p) {
  float r;
  asm volatile("global_load_dword %0, %1, off sc0 sc1\n\ts_waitcnt vmcnt(0)"
               : "=v"(r) : "v"(p) : "memory");
  return r;
}
__device__ __forceinline__ void st_cg_f32(float* p, float v) {
  asm volatile("global_store_dword %0, %1, off sc0 sc1" :: "v"(p), "v"(v) : "memory");
}
__device__ __forceinline__ f4 ld_cg_f4(const f4* p) {
  f4 r;
  asm volatile("global_load_dwordx4 %0, %1, off sc0 sc1\n\ts_waitcnt vmcnt(0)"
               : "=v"(r) : "v"(p) : "memory");
  return r;
}
__device__ __forceinline__ void st_cg_f4(f4* p, f4 v) {
  asm volatile("global_store_dwordx4 %0, %1, off sc0 sc1" :: "v"(p), "v"(v) : "memory");
}
__device__ __forceinline__ void ld4_cg(f4& r0, f4& r1, f4& r2, f4& r3,
                                       const f4* a0, const f4* a1,
                                       const f4* a2, const f4* a3) {
  asm volatile(
    "global_load_dwordx4 %0, %4, off sc0 sc1\n\t"
    "global_load_dwordx4 %1, %5, off sc0 sc1\n\t"
    "global_load_dwordx4 %2, %6, off sc0 sc1\n\t"
    "global_load_dwordx4 %3, %7, off sc0 sc1\n\t"
    "s_waitcnt vmcnt(0)"
    : "=&v"(r0), "=&v"(r1), "=&v"(r2), "=&v"(r3)
    : "v"(a0), "v"(a1), "v"(a2), "v"(a3)
    : "memory");
}
__device__ __forceinline__ void ld8_cg(f4& r0, f4& r1, f4& r2, f4& r3,
                                       f4& r4, f4& r5, f4& r6, f4& r7,
                                       const f4* a0, const f4* a1, const f4* a2,
                                       const f4* a3, const f4* a4, const f4* a5,
                                       const f4* a6, const f4* a7) {
  asm volatile(
    "global_load_dwordx4 %0, %8, off sc0 sc1\n\t"
    "global_load_dwordx4 %1, %9, off sc0 sc1\n\t"
    "global_load_dwordx4 %2, %10, off sc0 sc1\n\t"
    "global_load_dwordx4 %3, %11, off sc0 sc1\n\t"
    "global_load_dwordx4 %4, %12, off sc0 sc1\n\t"
    "global_load_dwordx4 %5, %13, off sc0 sc1\n\t"
    "global_load_dwordx4 %6, %14, off sc0 sc1\n\t"
    "global_load_dwordx4 %7, %15, off sc0 sc1\n\t"
    "s_waitcnt vmcnt(0)"
    : "=&v"(r0), "=&v"(r1), "=&v"(r2), "=&v"(r3),
      "=&v"(r4), "=&v"(r5), "=&v"(r6), "=&v"(r7)
    : "v"(a0), "v"(a1), "v"(a2), "v"(a3),
      "v"(a4), "v"(a5), "v"(a6), "v"(a7)
    : "memory");
}

// ---- all-to-all barriers: private arrival lines, direct polling ----
// producer: __syncthreads drains each wave's stores (vmcnt) before s_barrier,
// then t0's flag store is issued -> data at LLC before flag. consumer: poll
// completes before post-barrier cg loads are issued.
__device__ __forceinline__ void g_arrive(unsigned* bar, unsigned e) {
  __syncthreads();
  if (threadIdx.x == 0) st_cg_u32(bar + ARR_G + blockIdx.x * 16, e);
}
__device__ __forceinline__ void g_wait(unsigned* bar, unsigned e) {
  if (threadIdx.x < 256) {
    while (ld_cg_u32(bar + ARR_G + threadIdx.x * 16) < e) {}
  }
  __syncthreads();
}
__device__ __forceinline__ void l_arrive(unsigned* bar, unsigned e) {
  __syncthreads();
  if (threadIdx.x == 0) st_cg_u32(bar + ARR_L + blockIdx.x * 16, e);
}
__device__ __forceinline__ void l_wait(unsigned* bar, unsigned e, int b_grp) {
  if (threadIdx.x < 16) {
    while (ld_cg_u32(bar + ARR_L + (threadIdx.x * 16 + b_grp) * 16) < e) {}
  }
  __syncthreads();
}

// ---------------- init ----------------
__global__ void k_init(float* __restrict__ ws) {
  const int tid = threadIdx.x;
  float* awc = ws + OFF_AWC;
  float* qv  = ws + OFF_Q;
  unsigned* bar = (unsigned*)(ws + OFF_BAR);
  for (int i = tid; i < NB*TE; i += 256) st_cg_f32(awc + i, 0.0f);
  for (int i = tid; i < NB*ATT; i += 256) st_cg_f32(qv + i, 0.0f);
  for (int i = tid; i < BAR_U32; i += 256) st_cg_u32(bar + i, 0u);
}

// ---------------- prenet ----------------
__global__ void k_prenet(const float* __restrict__ mels,
                         const float* __restrict__ w1,
                         const float* __restrict__ w2,
                         float* __restrict__ x2) {
  const int t = blockIdx.x >> 4;
  const int b = blockIdx.x & 15;
  const int j = threadIdx.x;
  __shared__ float s_in[NMEL];
  __shared__ float s_x1[PREN];
  if (j < NMEL) s_in[j] = (t == 0) ? 0.0f : mels[(b*TD + (t-1))*NMEL + j];
  __syncthreads();
  float a1 = 0.0f;
  #pragma unroll 8
  for (int k = 0; k < NMEL; ++k) a1 += s_in[k] * w1[j*NMEL + k];
  s_x1[j] = fmaxf(a1, 0.0f);
  __syncthreads();
  float a2 = 0.0f;
  #pragma unroll 8
  for (int k = 0; k < PREN; ++k) a2 += s_x1[k] * w2[j*PREN + k];
  x2[(t*NB + b)*PREN + j] = fmaxf(a2, 0.0f);
}

// ---------------- processed encoder ----------------
__global__ void k_procenc(const float* __restrict__ enc,
                          const float* __restrict__ w,
                          float* __restrict__ pe) {
  const int bt = blockIdx.x;
  const int a = threadIdx.x;
  __shared__ float s_e[EE];
  for (int k = a; k < EE; k += 128) s_e[k] = enc[bt*EE + k];
  __syncthreads();
  float acc = 0.0f;
  #pragma unroll 8
  for (int k = 0; k < EE; ++k) acc += s_e[k] * w[a*EE + k];
  pe[bt*ATT + a] = acc;
}

// ---------------- main sequential decoder loop ----------------
__global__ void __launch_bounds__(512, 1) k_main(
    const float* __restrict__ enc,
    const float* __restrict__ lstm_proj_w,
    const float* __restrict__ loc_conv_w,
    const float* __restrict__ loc_conv_b,
    const float* __restrict__ loc_dense_w,
    const float* __restrict__ loc_dense_b,
    const float* __restrict__ e_w,
    const float* __restrict__ e_b,
    const float* __restrict__ w_ih0,
    const float* __restrict__ b_ih0,
    const float* __restrict__ b_hh0,
    const float* __restrict__ w_ih1,
    const float* __restrict__ b_ih1,
    const float* __restrict__ b_hh1,
    const float* __restrict__ proj_w,
    const float* __restrict__ proj_b,
    const float* __restrict__ stop_w,
    const float* __restrict__ stop_b,
    const int*   __restrict__ text_len,
    float* __restrict__ ws,
    float* __restrict__ out) {
  const int bid = blockIdx.x;   // 0..255
  const int tid = threadIdx.x;  // 0..511

  float* x2  = ws + OFF_X2;
  float* pe  = ws + OFF_PE;
  float* awc = ws + OFF_AWC;
  float* en  = ws + OFF_EN;
  float* qv  = ws + OFF_Q;
  float* ctx = ws + OFF_CTX;
  float* h1  = ws + OFF_H1;
  float* h2  = ws + OFF_H2;
  unsigned* bar = (unsigned*)(ws + OFF_BAR);

  __shared__ __align__(16) float s_ldw[NLOC*ATT];   // loc_dense_w^T [c][a]
  __shared__ float s_awc[64];
  __shared__ float s_loc[16*33];
  __shared__ float s_red[16];
  __shared__ float s_aw[256];
  __shared__ __align__(16) float s_dec[HH+EE];      // [h2 | ctx] for P5
  __shared__ float s_b0[12], s_b1[12];
  extern __shared__ __align__(16) float dynlds[];
  f4* lw0 = (f4*)dynlds;
  f4* lw1 = ((f4*)dynlds) + LW0_F4;

  const int b_grp = bid & 15;   // batch this block serves in P1/P2/P5
  const int sub   = bid >> 4;   // 0..15 chunk within group
  const int h0    = bid * 4;    // this block's 4 h-outputs in P3/P4

  // ---- one-time staging ----
  for (int i = tid; i < NLOC*ATT; i += 512) {
    int c = i >> 7, a = i & 127;
    s_ldw[i] = loc_dense_w[a*NLOC + c];
  }
  if (tid < 12) {
    int g = tid >> 2, h = tid & 3;
    int gr = (g == 0 ? 0 : (g == 1 ? 2048 : 3072)) + h0 + h;
    s_b0[tid] = b_ih0[gr] + b_hh0[gr];
    s_b1[tid] = b_ih1[gr] + b_hh1[gr];
  }
  {
    const f4* w0_4 = (const f4*)w_ih0;   // row stride 192 f4
    const f4* w1_4 = (const f4*)w_ih1;   // row stride 256 f4
    for (int i = tid; i < LW0_F4; i += 512) {
      int r = i / 192, c = i - r*192;
      int g = r >> 2, h = r & 3;
      int grow = (g == 0 ? 0 : (g == 1 ? 2048 : 3072)) + h0 + h;
      lw0[i] = w0_4[grow*192 + c];
    }
    for (int i = tid; i < LW1_F4; i += 512) {
      int r = i >> 8, c = i & 255;
      int g = r >> 2, h = r & 3;
      int grow = (g == 0 ? 0 : (g == 1 ? 2048 : 3072)) + h0 + h;
      lw1[i] = w1_4[grow*256 + c];
    }
  }
  const int   lenb = text_len[b_grp];
  const float eb0  = e_b[0];

  // per-thread loop-invariant registers
  const int tl = tid >> 5;          // 0..15 (P1 row)
  const int j  = tid & 31;          // 0..15 (P1 col quad)
  float lcw_r[KWW];                 // conv taps for c=j
  #pragma unroll
  for (int k = 0; k < KWW; ++k) lcw_r[k] = loc_conv_w[j*KWW + k];
  const float lcb_r = loc_conv_b[j];
  const f4 db_r = *(const f4*)(loc_dense_b + 4*j);
  const f4 ew_r = *(const f4*)(e_w + 4*j);
  const f4 pe_r = *(const f4*)(pe + (size_t)(b_grp*TE + sub*16 + tl)*ATT + 4*j);
  const f4 ps_r = pe_r + db_r;      // static part of pre-tanh term
  // P2 invariants: this thread's enc fragment (read-only -> registers)
  const int e4i = tid >> 6;         // 0..7
  const int ts  = tid & 63;         // 0..63
  f4 encr[4];
  {
    const f4* enc4 = (const f4*)(enc + (size_t)b_grp*TE*EE);
    #pragma unroll
    for (int i = 0; i < 4; ++i)
      encr[i] = enc4[(size_t)(ts + 64*i)*(EE/4) + sub*8 + e4i];
  }
  // P3/P4 mapping
  const int pb = tid >> 5;          // 0..15 : batch
  const int kc = tid & 31;          // k-split 32
  __syncthreads();

  unsigned eg = 0, el = 0;

  for (int t = 0; t < TD; ++t) {
    // ===== P1a (pre-work, needs only awc/prev-step state) =====
    f4 pre;
    {
      if (tid >= 128 && tid < 176) {
        const int i = tid - 128;     // 0..47
        const int g = sub*16 - PADW + i;
        s_awc[i] = (i < 46 && g >= 0 && g < TE) ? ld_cg_f32(awc + b_grp*TE + g)
                                                : 0.0f;
      }
      __syncthreads();
      float cv = lcb_r;
      #pragma unroll
      for (int k = 0; k < KWW; ++k) cv += s_awc[tl + k] * lcw_r[k];
      s_loc[tl*33 + j] = cv;
      __syncthreads();
      f4 d4 = (f4){0.f, 0.f, 0.f, 0.f};
      #pragma unroll 8
      for (int c = 0; c < NLOC; ++c) {
        const float lv = s_loc[tl*33 + c];
        const f4 w4 = ((const f4*)s_ldw)[c*32 + j];
        d4.x += lv*w4.x; d4.y += lv*w4.y; d4.z += lv*w4.z; d4.w += lv*w4.w;
      }
      pre = ps_r + d4;
    }
    l_wait(bar, el, b_grp);           // qv from prev P5 ready (t=0: passes)
    // ===== P1b: finish energies =====
    {
      const f4 q4 = ld_cg_f4((const f4*)qv + b_grp*32 + j);
      float acc = tanhf(pre.x+q4.x)*ew_r.x + tanhf(pre.y+q4.y)*ew_r.y
                + tanhf(pre.z+q4.z)*ew_r.z + tanhf(pre.w+q4.w)*ew_r.w;
      acc = red32(acc);
      if (j == 0) {
        float evv = acc + eb0;
        const int tt = sub*16 + tl;
        if (tt >= lenb) evv = -1e9f;
        st_cg_f32(en + b_grp*TE + tt, evv);
      }
    }
    l_arrive(bar, ++el);
    l_wait(bar, el, b_grp);
    // ===== P2: softmax + awc + ctx (enc already in registers) =====
    {
      float evv = 0.f, p = 0.f;
      if (tid < 256) {
        evv = ld_cg_f32(en + b_grp*TE + tid);
        float m = evv;
        #pragma unroll
        for (int d = 32; d > 0; d >>= 1) m = fmaxf(m, __shfl_xor(m, d));
        if ((tid & 63) == 0) s_red[tid >> 6] = m;
      }
      __syncthreads();
      const float mx = fmaxf(fmaxf(s_red[0], s_red[1]), fmaxf(s_red[2], s_red[3]));
      if (tid < 256) {
        p = expf(evv - mx);
        float sm = p;
        #pragma unroll
        for (int d = 32; d > 0; d >>= 1) sm += __shfl_xor(sm, d);
        if ((tid & 63) == 0) s_red[8 + (tid >> 6)] = sm;
      }
      __syncthreads();
      const float inv = 1.0f / (s_red[8] + s_red[9] + s_red[10] + s_red[11]);
      if (tid < 256) {
        const float aw = p * inv;
        s_aw[tid] = aw;
        if (sub == 0) {
          const float old = ld_cg_f32(awc + b_grp*TE + tid);
          st_cg_f32(awc + b_grp*TE + tid, old + aw);
        }
      }
      __syncthreads();
      f4 a4 = (f4){0.f, 0.f, 0.f, 0.f};
      #pragma unroll
      for (int i = 0; i < 4; ++i) {
        const float awv = s_aw[ts + 64*i];
        a4.x += awv*encr[i].x; a4.y += awv*encr[i].y;
        a4.z += awv*encr[i].z; a4.w += awv*encr[i].w;
      }
      #pragma unroll
      for (int d = 32; d > 0; d >>= 1) {
        a4.x += __shfl_down(a4.x, d);
        a4.y += __shfl_down(a4.y, d);
        a4.z += __shfl_down(a4.z, d);
        a4.w += __shfl_down(a4.w, d);
      }
      if (ts == 0) st_cg_f4((f4*)ctx + b_grp*(EE/4) + sub*8 + e4i, a4);
    }
    g_arrive(bar, ++eg);
    // ===== P3a: LSTM0 x-part (independent of ctx) =====
    float acc[12];
    {
      #pragma unroll
      for (int r = 0; r < 12; ++r) acc[r] = 0.0f;
      const f4* x4p = (const f4*)(x2 + (size_t)(t*NB + pb)*PREN);
      #pragma unroll
      for (int i = 0; i < 2; ++i) {
        const int kf = kc + 32*i;
        const f4 xv = x4p[kf];
        #pragma unroll
        for (int r = 0; r < 12; ++r) acc[r] += dot4(xv, lw0[r*192 + kf]);
      }
    }
    g_wait(bar, eg);                  // ctx ready
    // ===== P3b: LSTM0 ctx-part + gates =====
    {
      const f4* c4p = (const f4*)(ctx + pb*EE);
      f4 cv0, cv1, cv2, cv3;
      ld4_cg(cv0, cv1, cv2, cv3, c4p+kc, c4p+kc+32, c4p+kc+64, c4p+kc+96);
      #pragma unroll
      for (int r = 0; r < 12; ++r) {
        acc[r] += dot4(cv0, lw0[r*192 + 64 + kc]);
        acc[r] += dot4(cv1, lw0[r*192 + 64 + kc + 32]);
        acc[r] += dot4(cv2, lw0[r*192 + 64 + kc + 64]);
        acc[r] += dot4(cv3, lw0[r*192 + 64 + kc + 96]);
      }
      #pragma unroll
      for (int r = 0; r < 12; ++r) acc[r] = red32(acc[r]);
      if (kc == 0) {
        f4 hv;
        #pragma unroll
        for (int h = 0; h < 4; ++h) {
          const float gi = acc[h]   + s_b0[h];
          const float gg = acc[4+h] + s_b0[4+h];
          const float go = acc[8+h] + s_b0[8+h];
          const float c = sigmf(gi) * tanhf(gg);
          hv[h] = sigmf(go) * tanhf(c);
        }
        st_cg_f4((f4*)h1 + pb*(HH/4) + bid, hv);
      }
    }
    g_arrive(bar, ++eg);
    g_wait(bar, eg);                  // h1 ready
    // ===== P4: LSTM1 =====
    {
      #pragma unroll
      for (int r = 0; r < 12; ++r) acc[r] = 0.0f;
      const f4* h4p = (const f4*)(h1 + pb*HH);
      f4 hv0, hv1, hv2, hv3, hv4, hv5, hv6, hv7;
      ld8_cg(hv0, hv1, hv2, hv3, hv4, hv5, hv6, hv7,
             h4p+kc, h4p+kc+32, h4p+kc+64, h4p+kc+96,
             h4p+kc+128, h4p+kc+160, h4p+kc+192, h4p+kc+224);
      #pragma unroll
      for (int r = 0; r < 12; ++r) {
        acc[r] += dot4(hv0, lw1[r*256 + kc]);
        acc[r] += dot4(hv1, lw1[r*256 + kc + 32]);
        acc[r] += dot4(hv2, lw1[r*256 + kc + 64]);
        acc[r] += dot4(hv3, lw1[r*256 + kc + 96]);
        acc[r] += dot4(hv4, lw1[r*256 + kc + 128]);
        acc[r] += dot4(hv5, lw1[r*256 + kc + 160]);
        acc[r] += dot4(hv6, lw1[r*256 + kc + 192]);
        acc[r] += dot4(hv7, lw1[r*256 + kc + 224]);
      }
      #pragma unroll
      for (int r = 0; r < 12; ++r) acc[r] = red32(acc[r]);
      if (kc == 0) {
        f4 hv;
        #pragma unroll
        for (int h = 0; h < 4; ++h) {
          const float gi = acc[h]   + s_b1[h];
          const float gg = acc[4+h] + s_b1[4+h];
          const float go = acc[8+h] + s_b1[8+h];
          const float c = sigmf(gi) * tanhf(gg);
          hv[h] = sigmf(go) * tanhf(c);
        }
        st_cg_f4((f4*)h2 + pb*(HH/4) + bid, hv);
      }
    }
    g_arrive(bar, ++eg);
    // ===== P5a: preload ctx half of s_dec (independent of h2) =====
    if (tid >= 256 && tid < 384)
      ((f4*)s_dec)[tid] = ld_cg_f4((const f4*)ctx + b_grp*(EE/4) + (tid - 256));
    g_wait(bar, eg);                  // h2 ready
    // ===== P5b: qv (sub<8) ; mel/stop (sub>=8) =====
    {
      if (tid < 256)
        ((f4*)s_dec)[tid] = ld_cg_f4((const f4*)h2 + b_grp*(HH/4) + tid);
      __syncthreads();
      const int ol = tid >> 5;   // 0..15
      const int kq = tid & 31;
      const f4* s4 = (const f4*)s_dec;
      if (sub < 8) {
        const int a = sub*16 + ol;
        const f4* w4 = (const f4*)(lstm_proj_w + (size_t)a*HH);
        float a2 = 0.0f;
        #pragma unroll
        for (int i = 0; i < 8; ++i) a2 += dot4(s4[kq + 32*i], w4[kq + 32*i]);
        a2 = red32(a2);
        if (kq == 0) st_cg_f32(qv + b_grp*ATT + a, a2);
      } else {
        const int m = (sub - 8)*11 + ol;
        if (ol < 11 && m < 81) {
          const float* wrow = (m < NMEL) ? (proj_w + (size_t)m*(HH+EE)) : stop_w;
          const f4* w4 = (const f4*)wrow;
          float a2 = 0.0f;
          #pragma unroll
          for (int i = 0; i < 12; ++i) a2 += dot4(s4[kq + 32*i], w4[kq + 32*i]);
          a2 = red32(a2);
          if (kq == 0) {
            if (m < NMEL) out[(b_grp*TD + t)*NMEL + m] = a2 + proj_b[m];
            else          out[NB*TD*NMEL + b_grp*TD + t] = a2 + stop_b[0];
          }
        }
      }
    }
    l_arrive(bar, ++el);
  }
}

extern "C" void kernel_launch(void* const* d_in, const int* in_sizes, int n_in,
                              void* d_out, int out_size, void* d_ws, size_t ws_size,
                              hipStream_t stream) {
  (void)in_sizes; (void)n_in; (void)out_size; (void)ws_size;
  const float* enc         = (const float*)d_in[0];
  const float* mels        = (const float*)d_in[1];
  const float* enc_proj_w  = (const float*)d_in[2];
  const float* lstm_proj_w = (const float*)d_in[3];
  const float* loc_conv_w  = (const float*)d_in[4];
  const float* loc_conv_b  = (const float*)d_in[5];
  const float* loc_dense_w = (const float*)d_in[6];
  const float* loc_dense_b = (const float*)d_in[7];
  const float* e_w         = (const float*)d_in[8];
  const float* e_b         = (const float*)d_in[9];
  const float* prenet1_w   = (const float*)d_in[10];
  const float* prenet2_w   = (const float*)d_in[11];
  const float* w_ih0       = (const float*)d_in[12];
  const float* b_ih0       = (const float*)d_in[14];
  const float* b_hh0       = (const float*)d_in[15];
  const float* w_ih1       = (const float*)d_in[16];
  const float* b_ih1       = (const float*)d_in[18];
  const float* b_hh1       = (const float*)d_in[19];
  const float* proj_w      = (const float*)d_in[20];
  const float* proj_b      = (const float*)d_in[21];
  const float* stop_w      = (const float*)d_in[22];
  const float* stop_b      = (const float*)d_in[23];
  const int*   text_len    = (const int*)d_in[24];
  float* ws  = (float*)d_ws;
  float* out = (float*)d_out;

  static int attr_set = 0;
  if (!attr_set) {
    hipFuncSetAttribute((const void*)k_main,
                        hipFuncAttributeMaxDynamicSharedMemorySize, DYN_BYTES);
    attr_set = 1;
  }

  k_init<<<dim3(1), dim3(256), 0, stream>>>(ws);
  k_prenet<<<dim3(TD*NB), dim3(256), 0, stream>>>(mels, prenet1_w, prenet2_w, ws + OFF_X2);
  k_procenc<<<dim3(NB*TE), dim3(128), 0, stream>>>(enc, enc_proj_w, ws + OFF_PE);

  k_main<<<dim3(256), dim3(512), DYN_BYTES, stream>>>(
      enc, lstm_proj_w, loc_conv_w, loc_conv_b, loc_dense_w, loc_dense_b,
      e_w, e_b, w_ih0, b_ih0, b_hh0, w_ih1, b_ih1, b_hh1,
      proj_w, proj_b, stop_w, stop_b, text_len, ws, out);
}